// Round 7
// baseline (415.705 us; speedup 1.0000x reference)
//
#include <hip/hip_runtime.h>
#include <hip/hip_fp16.h>
#include <math.h>

#define LEAKY 0.2f
#define NB 24   // dst nodes per aggregation block

__device__ inline int h2i(__half2 h) { union { __half2 h; int i; } u; u.h = h; return u.i; }
__device__ inline __half2 i2h(int i) { union { __half2 h; int i; } u; u.i = i; return u.h; }

// ================= CSR build =================
__global__ __launch_bounds__(256) void k_hist(const int* __restrict__ ei,
                                              int* __restrict__ deg, int E, int Etot)
{
  int tid = blockIdx.x * 256 + threadIdx.x;
  if (tid >= Etot) return;
  int d = (tid < E) ? ei[E + tid] : tid - E;
  atomicAdd(&deg[d], 1);
}

__global__ __launch_bounds__(256) void k_scan_blk(const int* __restrict__ deg,
                                                  int* __restrict__ rowptr,
                                                  int* __restrict__ part, int N)
{
  __shared__ int ls[256];
  int t = threadIdx.x;
  int base = blockIdx.x * 1024 + t * 4;
  int d0 = (base     < N) ? deg[base]     : 0;
  int d1 = (base + 1 < N) ? deg[base + 1] : 0;
  int d2 = (base + 2 < N) ? deg[base + 2] : 0;
  int d3 = (base + 3 < N) ? deg[base + 3] : 0;
  int s = d0 + d1 + d2 + d3;
  ls[t] = s;
  __syncthreads();
  for (int off = 1; off < 256; off <<= 1) {
    int v = (t >= off) ? ls[t - off] : 0;
    __syncthreads();
    ls[t] += v;
    __syncthreads();
  }
  int excl = ls[t] - s;
  if (t == 255) part[blockIdx.x] = ls[255];
  if (base     <= N) rowptr[base]     = excl;
  if (base + 1 <= N) rowptr[base + 1] = excl + d0;
  if (base + 2 <= N) rowptr[base + 2] = excl + d0 + d1;
  if (base + 3 <= N) rowptr[base + 3] = excl + d0 + d1 + d2;
}

// add_off with the part-scan folded in (nb <= 64)
__global__ __launch_bounds__(256) void k_add_off(int* __restrict__ rowptr,
                                                 const int* __restrict__ part,
                                                 int* __restrict__ cur, int N, int nb)
{
  __shared__ int pexcl;
  int t = threadIdx.x;
  if (t < 64) {
    int v = (t < nb) ? part[t] : 0;
    int inc = v;
#pragma unroll
    for (int off = 1; off < 64; off <<= 1) {
      int u = __shfl_up(inc, off);
      if (t >= off) inc += u;
    }
    if (t == blockIdx.x) pexcl = inc - v;
  }
  __syncthreads();
  int p = pexcl;
  int base = blockIdx.x * 1024 + t * 4;
#pragma unroll
  for (int k = 0; k < 4; ++k) {
    int i = base + k;
    if (i <= N) {
      int v = rowptr[i] + p;
      rowptr[i] = v;
      if (i < N) cur[i] = v;
    }
  }
}

__global__ __launch_bounds__(256) void k_scatter(const int* __restrict__ ei,
                                                 int* __restrict__ cur,
                                                 int* __restrict__ colx, int E, int Etot)
{
  int tid = blockIdx.x * 256 + threadIdx.x;
  if (tid >= Etot) return;
  int s, d;
  if (tid < E) { s = ei[tid]; d = ei[E + tid]; }
  else { s = d = tid - E; }
  int pos = atomicAdd(&cur[d], 1);
  colx[pos] = s;
}

// ====== GEMM1: h1 = x @ W1 (N x 128 @ 128 x 128), fp16 h1 out, fused att dots ======
__global__ __launch_bounds__(256) void k_gemm1(
    const float* __restrict__ x, const float* __restrict__ W,
    const float* __restrict__ att_s, const float* __restrict__ att_d,
    unsigned* __restrict__ h1h, float* __restrict__ a1s, float* __restrict__ a1d, int N)
{
  __shared__ unsigned Wlh[128][64];   // half2-packed cols, 32KB
  __shared__ float Xl[64][128];       // 32KB
  int t = threadIdx.x;
  const float4* W4 = (const float4*)W;
#pragma unroll
  for (int i = 0; i < 16; ++i) {
    int id = t + i * 256;
    float4 wv = W4[id];
    Wlh[id >> 5][(id & 31) * 2]     = (unsigned)h2i(__floats2half2_rn(wv.x, wv.y));
    Wlh[id >> 5][(id & 31) * 2 + 1] = (unsigned)h2i(__floats2half2_rn(wv.z, wv.w));
  }
  int row0 = blockIdx.x * 64;
  const float4* X4 = (const float4*)x;
  float4* Xl4 = (float4*)&Xl[0][0];
#pragma unroll
  for (int i = 0; i < 8; ++i) {
    int id = t + i * 256;
    int r = id >> 5, c = id & 31;
    int gr = row0 + r;
    Xl4[id] = (gr < N) ? X4[(size_t)gr * 32 + c] : make_float4(0.f, 0.f, 0.f, 0.f);
  }
  __syncthreads();
  int cg = t & 31, rg = t >> 5;
  float acc[8][4] = {};
#pragma unroll 2
  for (int k = 0; k < 128; k += 4) {
    float4 xv[8];
#pragma unroll
    for (int rr = 0; rr < 8; ++rr) xv[rr] = *(const float4*)&Xl[rg * 8 + rr][k];
#pragma unroll
    for (int kk = 0; kk < 4; ++kk) {
      uint2 wp = *(const uint2*)&Wlh[k + kk][cg * 2];
      float2 w01 = __half22float2(i2h((int)wp.x));
      float2 w23 = __half22float2(i2h((int)wp.y));
#pragma unroll
      for (int rr = 0; rr < 8; ++rr) {
        float xs = (&xv[rr].x)[kk];
        acc[rr][0] = fmaf(xs, w01.x, acc[rr][0]);
        acc[rr][1] = fmaf(xs, w01.y, acc[rr][1]);
        acc[rr][2] = fmaf(xs, w23.x, acc[rr][2]);
        acc[rr][3] = fmaf(xs, w23.y, acc[rr][3]);
      }
    }
  }
  int col = cg * 4;
  int h = (t >> 4) & 1;
  float4 asv = *(const float4*)&att_s[col];
  float4 adv = *(const float4*)&att_d[col];
#pragma unroll
  for (int rr = 0; rr < 8; ++rr) {
    int gr = row0 + rg * 8 + rr;
    float ps = acc[rr][0] * asv.x + acc[rr][1] * asv.y + acc[rr][2] * asv.z + acc[rr][3] * asv.w;
    float pd = acc[rr][0] * adv.x + acc[rr][1] * adv.y + acc[rr][2] * adv.z + acc[rr][3] * adv.w;
    ps += __shfl_xor(ps, 1); ps += __shfl_xor(ps, 2); ps += __shfl_xor(ps, 4); ps += __shfl_xor(ps, 8);
    pd += __shfl_xor(pd, 1); pd += __shfl_xor(pd, 2); pd += __shfl_xor(pd, 4); pd += __shfl_xor(pd, 8);
    if (gr < N) {
      unsigned p01 = (unsigned)h2i(__floats2half2_rn(acc[rr][0], acc[rr][1]));
      unsigned p23 = (unsigned)h2i(__floats2half2_rn(acc[rr][2], acc[rr][3]));
      *(uint2*)&h1h[(size_t)gr * 64 + cg * 2] = make_uint2(p01, p23);
      if ((t & 15) == 0) { a1s[gr * 2 + h] = ps; a1d[gr * 2 + h] = pd; }
    }
  }
}

// ====== Aggregate layer 1: block owns NB dst nodes, wave-per-edge, LDS accumulators ======
// Whole wave processes one edge (64 lanes x uint = full 256B h-row). Branches wave-uniform.
// Chain per edge: colx -> {a1s, row} (2 levels), 2 edges in flight (manual 2-wide).
__global__ __launch_bounds__(256) void k_agg1(
    const int* __restrict__ rowptr, const int* __restrict__ colx,
    const unsigned* __restrict__ h1h, const float* __restrict__ a1s,
    const float* __restrict__ a1d, const float* __restrict__ b1,
    unsigned* __restrict__ v1h, float* __restrict__ stats, int N)
{
  __shared__ float facc[NB][128];   // feat f=2l+i stored at [i*64+l]
  __shared__ float sacc[NB][2];
  __shared__ int rp[NB + 1];
  __shared__ float lsum[128], lsq[128];
  int t = threadIdx.x, l = t & 63, wv = t >> 6;
  int n0 = blockIdx.x * NB;
  int nb = N - n0; if (nb > NB) nb = NB;
  for (int i = t; i < NB * 128; i += 256) ((float*)facc)[i] = 0.f;
  if (t < NB * 2) ((float*)sacc)[t] = 0.f;
  if (t < 128) { lsum[t] = 0.f; lsq[t] = 0.f; }
  if (t <= nb) rp[t] = rowptr[n0 + t];
  __syncthreads();
  int E0 = rp[0], E1 = rp[nb];
  int nE = E1 - E0;
  int len = (nE + 3) >> 2;
  int p = E0 + wv * len;
  int p1 = p + len; if (p1 > E1) p1 = E1;
  bool head = l >= 32;
  if (p < p1) {
    int lo = 0, hi = nb - 1;
    while (lo < hi) { int mid = (lo + hi + 1) >> 1; if (rp[mid] <= p) lo = mid; else hi = mid - 1; }
    int d = lo;
    while (p < p1) {
      int rend = rp[d + 1]; if (rend > p1) rend = p1;
      float2 ad = *(const float2*)&a1d[(size_t)(n0 + d) * 2];
      float a0 = 0.f, a1 = 0.f, sew0 = 0.f, sew1 = 0.f;
      for (; p + 1 < rend; p += 2) {
        int s0 = colx[p], s1 = colx[p + 1];
        float2 av0 = *(const float2*)&a1s[(size_t)s0 * 2];
        float2 av1 = *(const float2*)&a1s[(size_t)s1 * 2];
        unsigned rv0 = h1h[(size_t)s0 * 64 + l];
        unsigned rv1 = h1h[(size_t)s1 * 64 + l];
        float x0 = av0.x + ad.x, x1 = av0.y + ad.y;
        float y0 = av1.x + ad.x, y1 = av1.y + ad.y;
        x0 = (x0 > 0.f) ? x0 : LEAKY * x0;
        x1 = (x1 > 0.f) ? x1 : LEAKY * x1;
        y0 = (y0 > 0.f) ? y0 : LEAKY * y0;
        y1 = (y1 > 0.f) ? y1 : LEAKY * y1;
        float e0 = __expf(x0), e1 = __expf(x1);
        float f0 = __expf(y0), f1 = __expf(y1);
        sew0 += e0 + f0; sew1 += e1 + f1;
        float2 r0 = __half22float2(i2h((int)rv0));
        float2 r1 = __half22float2(i2h((int)rv1));
        float wg0 = head ? e1 : e0;
        float wg1 = head ? f1 : f0;
        a0 = fmaf(wg0, r0.x, a0); a1 = fmaf(wg0, r0.y, a1);
        a0 = fmaf(wg1, r1.x, a0); a1 = fmaf(wg1, r1.y, a1);
      }
      if (p < rend) {
        int s0 = colx[p];
        float2 av0 = *(const float2*)&a1s[(size_t)s0 * 2];
        unsigned rv0 = h1h[(size_t)s0 * 64 + l];
        float x0 = av0.x + ad.x, x1 = av0.y + ad.y;
        x0 = (x0 > 0.f) ? x0 : LEAKY * x0;
        x1 = (x1 > 0.f) ? x1 : LEAKY * x1;
        float e0 = __expf(x0), e1 = __expf(x1);
        sew0 += e0; sew1 += e1;
        float2 r0 = __half22float2(i2h((int)rv0));
        float wg0 = head ? e1 : e0;
        a0 = fmaf(wg0, r0.x, a0); a1 = fmaf(wg0, r0.y, a1);
        ++p;
      }
      atomicAdd(&facc[d][l], a0);
      atomicAdd(&facc[d][64 + l], a1);
      if (l == 0) atomicAdd(&sacc[d][0], sew0);
      if (l == 1) atomicAdd(&sacc[d][1], sew1);
      ++d;
    }
  }
  __syncthreads();
  // finalize: uint u holds feats 2u (slot u), 2u+1 (slot 64+u); head = u>>5
  int u = l, dg = wv;
  float2 bias = *(const float2*)&b1[u * 2];
  float s0 = 0.f, s1 = 0.f, q0 = 0.f, q1 = 0.f;
  for (int d = dg; d < nb; d += 4) {
    float inv = 1.f / sacc[d][u >> 5];
    float o0 = fmaf(facc[d][u], inv, bias.x);
    float o1 = fmaf(facc[d][64 + u], inv, bias.y);
    v1h[(size_t)(n0 + d) * 64 + u] = (unsigned)h2i(__floats2half2_rn(o0, o1));
    s0 += o0; q0 += o0 * o0; s1 += o1; q1 += o1 * o1;
  }
  atomicAdd(&lsum[2 * u], s0); atomicAdd(&lsum[2 * u + 1], s1);
  atomicAdd(&lsq[2 * u], q0);  atomicAdd(&lsq[2 * u + 1], q1);
  __syncthreads();
  if (t < 128) { atomicAdd(&stats[t], lsum[t]); atomicAdd(&stats[128 + t], lsq[t]); }
}

// ====== GEMM2: h2 = relu(bn(v1h)) @ W2 (N x 128 @ 128 x 64), padded Xl, BN in-block ======
__global__ __launch_bounds__(256) void k_gemm2(
    const unsigned* __restrict__ v1h, const float* __restrict__ W2,
    const float* __restrict__ stats, const float* __restrict__ g1, const float* __restrict__ be1,
    const float* __restrict__ att_s, const float* __restrict__ att_d,
    unsigned* __restrict__ h2h, float* __restrict__ a2s, float* __restrict__ a2d,
    int N, float rcpN)
{
  __shared__ float Wl[128][64];
  __shared__ float Xl[64][132];
  __shared__ float kc[128], sc[128];
  int t = threadIdx.x;
  if (t < 128) {
    float mu = stats[t] * rcpN;
    float var = stats[128 + t] * rcpN - mu * mu;
    float kk = g1[t] * rsqrtf(var + 1e-5f);
    kc[t] = kk; sc[t] = be1[t] - mu * kk;
  }
  const float4* W4 = (const float4*)W2;
  float4* Wl4 = (float4*)&Wl[0][0];
#pragma unroll
  for (int i = 0; i < 8; ++i) Wl4[t + i * 256] = W4[t + i * 256];
  __syncthreads();
  int row0 = blockIdx.x * 64;
#pragma unroll
  for (int i = 0; i < 8; ++i) {
    int id = t + i * 256;
    int r = id >> 5, c4 = id & 31;
    int gr = row0 + r;
    uint2 pv = (gr < N) ? *(const uint2*)&v1h[(size_t)gr * 64 + c4 * 2] : make_uint2(0, 0);
    float2 a01 = __half22float2(i2h((int)pv.x));
    float2 a23 = __half22float2(i2h((int)pv.y));
    int f0 = c4 * 4;
    float4 o;
    o.x = fmaxf(a01.x * kc[f0]     + sc[f0],     0.f);
    o.y = fmaxf(a01.y * kc[f0 + 1] + sc[f0 + 1], 0.f);
    o.z = fmaxf(a23.x * kc[f0 + 2] + sc[f0 + 2], 0.f);
    o.w = fmaxf(a23.y * kc[f0 + 3] + sc[f0 + 3], 0.f);
    *(float4*)&Xl[r][c4 * 4] = o;
  }
  __syncthreads();
  int cg = t & 15, rg = t >> 4;
  float acc[4][4] = {};
#pragma unroll 2
  for (int k = 0; k < 128; k += 4) {
    float4 xv[4];
#pragma unroll
    for (int rr = 0; rr < 4; ++rr) xv[rr] = *(const float4*)&Xl[rg * 4 + rr][k];
#pragma unroll
    for (int kk = 0; kk < 4; ++kk) {
      float4 wv = *(const float4*)&Wl[k + kk][cg * 4];
#pragma unroll
      for (int rr = 0; rr < 4; ++rr) {
        float xs = (&xv[rr].x)[kk];
        acc[rr][0] = fmaf(xs, wv.x, acc[rr][0]);
        acc[rr][1] = fmaf(xs, wv.y, acc[rr][1]);
        acc[rr][2] = fmaf(xs, wv.z, acc[rr][2]);
        acc[rr][3] = fmaf(xs, wv.w, acc[rr][3]);
      }
    }
  }
  int col = cg * 4;
  float4 asv = *(const float4*)&att_s[col];
  float4 adv = *(const float4*)&att_d[col];
#pragma unroll
  for (int rr = 0; rr < 4; ++rr) {
    int gr = row0 + rg * 4 + rr;
    float ps = acc[rr][0] * asv.x + acc[rr][1] * asv.y + acc[rr][2] * asv.z + acc[rr][3] * asv.w;
    float pd = acc[rr][0] * adv.x + acc[rr][1] * adv.y + acc[rr][2] * adv.z + acc[rr][3] * adv.w;
    ps += __shfl_xor(ps, 1); ps += __shfl_xor(ps, 2); ps += __shfl_xor(ps, 4); ps += __shfl_xor(ps, 8);
    pd += __shfl_xor(pd, 1); pd += __shfl_xor(pd, 2); pd += __shfl_xor(pd, 4); pd += __shfl_xor(pd, 8);
    if (gr < N) {
      unsigned p01 = (unsigned)h2i(__floats2half2_rn(acc[rr][0], acc[rr][1]));
      unsigned p23 = (unsigned)h2i(__floats2half2_rn(acc[rr][2], acc[rr][3]));
      *(uint2*)&h2h[(size_t)gr * 32 + cg * 2] = make_uint2(p01, p23);
      if ((t & 15) == 0) { a2s[gr] = ps; a2d[gr] = pd; }
    }
  }
}

// ====== Aggregate layer 2: same structure, 64 feats, half load per lane ======
__global__ __launch_bounds__(256) void k_agg2(
    const int* __restrict__ rowptr, const int* __restrict__ colx,
    const __half* __restrict__ h2hh, const float* __restrict__ a2s,
    const float* __restrict__ a2d, const float* __restrict__ b2,
    unsigned* __restrict__ v2h, float* __restrict__ stats, int N)
{
  __shared__ float facc[NB][64];    // feat f at [f]
  __shared__ float sacc[NB];
  __shared__ int rp[NB + 1];
  __shared__ float lsum[64], lsq[64];
  int t = threadIdx.x, l = t & 63, wv = t >> 6;
  int n0 = blockIdx.x * NB;
  int nb = N - n0; if (nb > NB) nb = NB;
  for (int i = t; i < NB * 64; i += 256) ((float*)facc)[i] = 0.f;
  if (t < NB) sacc[t] = 0.f;
  if (t < 64) { lsum[t] = 0.f; lsq[t] = 0.f; }
  if (t <= nb) rp[t] = rowptr[n0 + t];
  __syncthreads();
  int E0 = rp[0], E1 = rp[nb];
  int nE = E1 - E0;
  int len = (nE + 3) >> 2;
  int p = E0 + wv * len;
  int p1 = p + len; if (p1 > E1) p1 = E1;
  if (p < p1) {
    int lo = 0, hi = nb - 1;
    while (lo < hi) { int mid = (lo + hi + 1) >> 1; if (rp[mid] <= p) lo = mid; else hi = mid - 1; }
    int d = lo;
    while (p < p1) {
      int rend = rp[d + 1]; if (rend > p1) rend = p1;
      float ad = a2d[n0 + d];
      float a0 = 0.f, sew = 0.f;
      for (; p + 1 < rend; p += 2) {
        int s0 = colx[p], s1 = colx[p + 1];
        float av0 = a2s[s0], av1 = a2s[s1];
        float r0 = __half2float(h2hh[(size_t)s0 * 64 + l]);
        float r1 = __half2float(h2hh[(size_t)s1 * 64 + l]);
        float x0 = av0 + ad, x1 = av1 + ad;
        x0 = (x0 > 0.f) ? x0 : LEAKY * x0;
        x1 = (x1 > 0.f) ? x1 : LEAKY * x1;
        float e0 = __expf(x0), e1 = __expf(x1);
        sew += e0 + e1;
        a0 = fmaf(e0, r0, a0);
        a0 = fmaf(e1, r1, a0);
      }
      if (p < rend) {
        int s0 = colx[p];
        float av0 = a2s[s0];
        float r0 = __half2float(h2hh[(size_t)s0 * 64 + l]);
        float x0 = av0 + ad;
        x0 = (x0 > 0.f) ? x0 : LEAKY * x0;
        float e0 = __expf(x0);
        sew += e0;
        a0 = fmaf(e0, r0, a0);
        ++p;
      }
      atomicAdd(&facc[d][l], a0);
      if (l == 0) atomicAdd(&sacc[d], sew);
      ++d;
    }
  }
  __syncthreads();
  // finalize: uint u holds feats 2u, 2u+1; threads: u = t&31, dgrp = t>>5 (8 groups)
  int u = t & 31, dg = t >> 5;
  float2 bias = *(const float2*)&b2[u * 2];
  float s0 = 0.f, s1 = 0.f, q0 = 0.f, q1 = 0.f;
  for (int d = dg; d < nb; d += 8) {
    float inv = 1.f / sacc[d];
    float o0 = fmaf(facc[d][2 * u], inv, bias.x);
    float o1 = fmaf(facc[d][2 * u + 1], inv, bias.y);
    v2h[(size_t)(n0 + d) * 32 + u] = (unsigned)h2i(__floats2half2_rn(o0, o1));
    s0 += o0; q0 += o0 * o0; s1 += o1; q1 += o1 * o1;
  }
  atomicAdd(&lsum[2 * u], s0); atomicAdd(&lsum[2 * u + 1], s1);
  atomicAdd(&lsq[2 * u], q0);  atomicAdd(&lsq[2 * u + 1], q1);
  __syncthreads();
  if (t < 64) { atomicAdd(&stats[t], lsum[t]); atomicAdd(&stats[64 + t], lsq[t]); }
}

// ================= Final: out = relu(bn(v2h)) @ linW + linb, BN inline =================
__global__ __launch_bounds__(256) void k_out(
    const __half* __restrict__ v2h, const float* __restrict__ stats,
    const float* __restrict__ g2, const float* __restrict__ be2,
    const float* __restrict__ linW, const float* __restrict__ linb,
    float* __restrict__ out, int N, float rcpN)
{
  int lane = threadIdx.x & 63;
  int n = blockIdx.x * 4 + (threadIdx.x >> 6);
  if (n >= N) return;
  float mu = stats[lane] * rcpN;
  float var = stats[64 + lane] * rcpN - mu * mu;
  float kk = g2[lane] * rsqrtf(var + 1e-5f);
  float sh = be2[lane] - mu * kk;
  float v = __half2float(v2h[(size_t)n * 64 + lane]);
  float hn = fmaxf(v * kk + sh, 0.f);
  float p = hn * linW[lane];
#pragma unroll
  for (int off = 32; off; off >>= 1) p += __shfl_xor(p, off);
  if (lane == 0) out[n] = p + linb[0];
}

extern "C" void kernel_launch(void* const* d_in, const int* in_sizes, int n_in,
                              void* d_out, int out_size, void* d_ws, size_t ws_size,
                              hipStream_t stream)
{
  const float* x    = (const float*)d_in[0];
  const int*   ei   = (const int*)d_in[1];
  const float* W1   = (const float*)d_in[2];
  const float* as1  = (const float*)d_in[3];
  const float* ad1  = (const float*)d_in[4];
  const float* b1   = (const float*)d_in[5];
  const float* g1   = (const float*)d_in[6];
  const float* be1  = (const float*)d_in[7];
  const float* W2   = (const float*)d_in[8];
  const float* as2  = (const float*)d_in[9];
  const float* ad2  = (const float*)d_in[10];
  const float* b2   = (const float*)d_in[11];
  const float* g2   = (const float*)d_in[12];
  const float* be2  = (const float*)d_in[13];
  const float* linW = (const float*)d_in[14];
  const float* linb = (const float*)d_in[15];
  float* out = (float*)d_out;

  int N = in_sizes[0] / 128;
  int E = in_sizes[1] / 2;
  int Etot = E + N;
  float rcpN = 1.f / (float)N;

  float* ws = (float*)d_ws;
  size_t o = 0;
  float* H1HF = ws + o; o += (size_t)N * 64;   // h1 fp16 (N x 128 halves); later h2h (N x 64 halves)
  float* V1HF = ws + o; o += (size_t)N * 64;   // v1 fp16; later v2h
  float* A1S  = ws + o; o += (size_t)N * 2;
  float* A1D  = ws + o; o += (size_t)N * 2;
  float* A2S  = ws + o; o += N;
  float* A2D  = ws + o; o += N;
  float* ST1  = ws + o; o += 256;              // zero-region start
  float* ST2  = ws + o; o += 128;              // zero-region end (384 floats)
  int* ROWPTR = (int*)(ws + o); o += (size_t)N + 1;
  int* COL    = (int*)(ws + o); o += (size_t)Etot;
  int* DEG    = (int*)(ws + o); o += N;
  int* PART   = (int*)(ws + o); o += 64;
  unsigned* H1H = (unsigned*)H1HF;
  unsigned* H2H = (unsigned*)H1HF;
  unsigned* V1H = (unsigned*)V1HF;
  unsigned* V2H = (unsigned*)V1HF;

  hipMemsetAsync(ST1, 0, 384 * 4, stream);
  hipMemsetAsync(DEG, 0, (size_t)N * 4, stream);

  int ebk = (Etot + 255) / 256;
  int nb = (N + 1024) / 1024;
  int gb = (N + 63) / 64;
  int ab = (N + NB - 1) / NB;

  k_hist<<<ebk, 256, 0, stream>>>(ei, DEG, E, Etot);
  k_scan_blk<<<nb, 256, 0, stream>>>(DEG, ROWPTR, PART, N);
  k_add_off<<<nb, 256, 0, stream>>>(ROWPTR, PART, DEG, N, nb);
  k_scatter<<<ebk, 256, 0, stream>>>(ei, DEG, COL, E, Etot);

  k_gemm1<<<gb, 256, 0, stream>>>(x, W1, as1, ad1, H1H, A1S, A1D, N);
  k_agg1<<<ab, 256, 0, stream>>>(ROWPTR, COL, H1H, A1S, A1D, b1, V1H, ST1, N);
  k_gemm2<<<gb, 256, 0, stream>>>(V1H, W2, ST1, g1, be1, as2, ad2, H2H, A2S, A2D, N, rcpN);
  k_agg2<<<ab, 256, 0, stream>>>(ROWPTR, COL, (const __half*)H2H, A2S, A2D, b2, V2H, ST2, N);
  k_out<<<(N + 3) / 4, 256, 0, stream>>>((const __half*)V2H, ST2, g2, be2, linW, linb, out, N, rcpN);
}

// Round 8
// 318.934 us; speedup vs baseline: 1.3034x; 1.3034x over previous
//
#include <hip/hip_runtime.h>
#include <hip/hip_fp16.h>
#include <math.h>

#define LEAKY 0.2f

__device__ inline int h2i(__half2 h) { union { __half2 h; int i; } u; u.h = h; return u.i; }
__device__ inline __half2 i2h(int i) { union { __half2 h; int i; } u; u.i = i; return u.h; }

// ================= CSR build =================
__global__ __launch_bounds__(256) void k_hist(const int* __restrict__ ei,
                                              int* __restrict__ deg, int E, int Etot)
{
  int tid = blockIdx.x * 256 + threadIdx.x;
  if (tid >= Etot) return;
  int d = (tid < E) ? ei[E + tid] : tid - E;
  atomicAdd(&deg[d], 1);
}

__global__ __launch_bounds__(256) void k_scan_blk(const int* __restrict__ deg,
                                                  int* __restrict__ rowptr,
                                                  int* __restrict__ part, int N)
{
  __shared__ int ls[256];
  int t = threadIdx.x;
  int base = blockIdx.x * 1024 + t * 4;
  int d0 = (base     < N) ? deg[base]     : 0;
  int d1 = (base + 1 < N) ? deg[base + 1] : 0;
  int d2 = (base + 2 < N) ? deg[base + 2] : 0;
  int d3 = (base + 3 < N) ? deg[base + 3] : 0;
  int s = d0 + d1 + d2 + d3;
  ls[t] = s;
  __syncthreads();
  for (int off = 1; off < 256; off <<= 1) {
    int v = (t >= off) ? ls[t - off] : 0;
    __syncthreads();
    ls[t] += v;
    __syncthreads();
  }
  int excl = ls[t] - s;
  if (t == 255) part[blockIdx.x] = ls[255];
  if (base     <= N) rowptr[base]     = excl;
  if (base + 1 <= N) rowptr[base + 1] = excl + d0;
  if (base + 2 <= N) rowptr[base + 2] = excl + d0 + d1;
  if (base + 3 <= N) rowptr[base + 3] = excl + d0 + d1 + d2;
}

// add_off with the part-scan folded in (nb <= 64 required; N=50000 -> nb=49)
__global__ __launch_bounds__(256) void k_add_off(int* __restrict__ rowptr,
                                                 const int* __restrict__ part,
                                                 int* __restrict__ cur, int N, int nb)
{
  __shared__ int pexcl;
  int t = threadIdx.x;
  if (t < 64) {
    int v = (t < nb) ? part[t] : 0;
    int inc = v;
#pragma unroll
    for (int off = 1; off < 64; off <<= 1) {
      int u = __shfl_up(inc, off);
      if (t >= off) inc += u;
    }
    if (t == blockIdx.x) pexcl = inc - v;
  }
  __syncthreads();
  int p = pexcl;
  int base = blockIdx.x * 1024 + t * 4;
#pragma unroll
  for (int k = 0; k < 4; ++k) {
    int i = base + k;
    if (i <= N) {
      int v = rowptr[i] + p;
      rowptr[i] = v;
      if (i < N) cur[i] = v;
    }
  }
}

__global__ __launch_bounds__(256) void k_scatter(const int* __restrict__ ei,
                                                 int* __restrict__ cur,
                                                 int* __restrict__ colx, int E, int Etot)
{
  int tid = blockIdx.x * 256 + threadIdx.x;
  if (tid >= Etot) return;
  int s, d;
  if (tid < E) { s = ei[tid]; d = ei[E + tid]; }
  else { s = d = tid - E; }
  int pos = atomicAdd(&cur[d], 1);
  colx[pos] = s;
}

// ====== GEMM1: h1 = x @ W1 (N x 128 @ 128 x 128), fp16 h1 out, fused att dots ======
__global__ __launch_bounds__(256) void k_gemm1(
    const float* __restrict__ x, const float* __restrict__ W,
    const float* __restrict__ att_s, const float* __restrict__ att_d,
    unsigned* __restrict__ h1h, float* __restrict__ a1s, float* __restrict__ a1d, int N)
{
  __shared__ unsigned Wlh[128][64];   // half2-packed cols, 32KB
  __shared__ float Xl[64][128];       // 32KB
  int t = threadIdx.x;
  const float4* W4 = (const float4*)W;
#pragma unroll
  for (int i = 0; i < 16; ++i) {
    int id = t + i * 256;
    float4 wv = W4[id];
    Wlh[id >> 5][(id & 31) * 2]     = (unsigned)h2i(__floats2half2_rn(wv.x, wv.y));
    Wlh[id >> 5][(id & 31) * 2 + 1] = (unsigned)h2i(__floats2half2_rn(wv.z, wv.w));
  }
  int row0 = blockIdx.x * 64;
  const float4* X4 = (const float4*)x;
  float4* Xl4 = (float4*)&Xl[0][0];
#pragma unroll
  for (int i = 0; i < 8; ++i) {
    int id = t + i * 256;
    int r = id >> 5, c = id & 31;
    int gr = row0 + r;
    Xl4[id] = (gr < N) ? X4[(size_t)gr * 32 + c] : make_float4(0.f, 0.f, 0.f, 0.f);
  }
  __syncthreads();
  int cg = t & 31, rg = t >> 5;
  float acc[8][4] = {};
#pragma unroll 2
  for (int k = 0; k < 128; k += 4) {
    float4 xv[8];
#pragma unroll
    for (int rr = 0; rr < 8; ++rr) xv[rr] = *(const float4*)&Xl[rg * 8 + rr][k];
#pragma unroll
    for (int kk = 0; kk < 4; ++kk) {
      uint2 wp = *(const uint2*)&Wlh[k + kk][cg * 2];
      float2 w01 = __half22float2(i2h((int)wp.x));
      float2 w23 = __half22float2(i2h((int)wp.y));
#pragma unroll
      for (int rr = 0; rr < 8; ++rr) {
        float xs = (&xv[rr].x)[kk];
        acc[rr][0] = fmaf(xs, w01.x, acc[rr][0]);
        acc[rr][1] = fmaf(xs, w01.y, acc[rr][1]);
        acc[rr][2] = fmaf(xs, w23.x, acc[rr][2]);
        acc[rr][3] = fmaf(xs, w23.y, acc[rr][3]);
      }
    }
  }
  int col = cg * 4;
  int h = (t >> 4) & 1;
  float4 asv = *(const float4*)&att_s[col];
  float4 adv = *(const float4*)&att_d[col];
#pragma unroll
  for (int rr = 0; rr < 8; ++rr) {
    int gr = row0 + rg * 8 + rr;
    float ps = acc[rr][0] * asv.x + acc[rr][1] * asv.y + acc[rr][2] * asv.z + acc[rr][3] * asv.w;
    float pd = acc[rr][0] * adv.x + acc[rr][1] * adv.y + acc[rr][2] * adv.z + acc[rr][3] * adv.w;
    ps += __shfl_xor(ps, 1); ps += __shfl_xor(ps, 2); ps += __shfl_xor(ps, 4); ps += __shfl_xor(ps, 8);
    pd += __shfl_xor(pd, 1); pd += __shfl_xor(pd, 2); pd += __shfl_xor(pd, 4); pd += __shfl_xor(pd, 8);
    if (gr < N) {
      unsigned p01 = (unsigned)h2i(__floats2half2_rn(acc[rr][0], acc[rr][1]));
      unsigned p23 = (unsigned)h2i(__floats2half2_rn(acc[rr][2], acc[rr][3]));
      *(uint2*)&h1h[(size_t)gr * 64 + cg * 2] = make_uint2(p01, p23);
      if ((t & 15) == 0) { a1s[gr * 2 + h] = ps; a1d[gr * 2 + h] = pd; }
    }
  }
}

// ====== Aggregate layer 1: TWO nodes per wave (32 lanes each, 4 feats/lane via uint2),
//        16 rows in flight per half-wave ======
__global__ __launch_bounds__(256) void k_agg1(
    const int* __restrict__ rowptr, const int* __restrict__ colx,
    const unsigned* __restrict__ h1h, const float* __restrict__ a1s,
    const float* __restrict__ a1d, const float* __restrict__ b1,
    unsigned* __restrict__ v1h, float* __restrict__ stats, int N, int TW)
{
  int t = threadIdx.x;
  int w = t >> 6, lane = t & 63;
  int g = lane >> 5, q = lane & 31;
  bool hi = q >= 16;                  // features 4q..4q+3 -> head = q>=16
  float4 bias = *(const float4*)&b1[q * 4];
  float4 bns = {0,0,0,0}, bnq = {0,0,0,0};
  int W = blockIdx.x * 4 + w;
  int iters = (N + 2 * TW - 1) / (2 * TW);
  for (int it = 0; it < iters; ++it) {
    int n = (it * TW + W) * 2 + g;
    bool act = n < N;
    int start = 0, end = 0;
    float2 ad = make_float2(0.f, 0.f);
    if (act) {
      start = rowptr[n]; end = rowptr[n + 1];
      ad = *(const float2*)&a1d[n * 2];
    }
    float se = 0.f;
    float4 acc = {0,0,0,0};
    for (int base = start; base < end; base += 32) {
      int cnt = end - base; if (cnt > 32) cnt = 32;
      int sl = 0, epk = 0;
      if (q < cnt) {
        sl = colx[base + q];
        float2 av = *(const float2*)&a1s[sl * 2];
        float x0 = av.x + ad.x, x1 = av.y + ad.y;
        x0 = (x0 > 0.f) ? x0 : LEAKY * x0;
        x1 = (x1 > 0.f) ? x1 : LEAKY * x1;
        epk = h2i(__floats2half2_rn(__expf(x0), __expf(x1)));
      }
      int j = 0;
      int lim16 = cnt & ~15;
      for (; j < lim16; j += 16) {
        int ss[16], ee[16];
#pragma unroll
        for (int k = 0; k < 16; ++k) { ss[k] = __shfl(sl, j + k, 32); ee[k] = __shfl(epk, j + k, 32); }
        uint2 rr[16];
#pragma unroll
        for (int k = 0; k < 16; ++k) rr[k] = *(const uint2*)&h1h[(size_t)ss[k] * 64 + q * 2];
#pragma unroll
        for (int k = 0; k < 16; ++k) {
          float2 ef = __half22float2(i2h(ee[k]));
          float wg = hi ? ef.y : ef.x;
          float2 r01 = __half22float2(i2h((int)rr[k].x));
          float2 r23 = __half22float2(i2h((int)rr[k].y));
          se += wg;
          acc.x = fmaf(wg, r01.x, acc.x);
          acc.y = fmaf(wg, r01.y, acc.y);
          acc.z = fmaf(wg, r23.x, acc.z);
          acc.w = fmaf(wg, r23.y, acc.w);
        }
      }
      int lim8 = cnt & ~7;
      for (; j < lim8; j += 8) {
        int ss[8], ee[8];
#pragma unroll
        for (int k = 0; k < 8; ++k) { ss[k] = __shfl(sl, j + k, 32); ee[k] = __shfl(epk, j + k, 32); }
        uint2 rr[8];
#pragma unroll
        for (int k = 0; k < 8; ++k) rr[k] = *(const uint2*)&h1h[(size_t)ss[k] * 64 + q * 2];
#pragma unroll
        for (int k = 0; k < 8; ++k) {
          float2 ef = __half22float2(i2h(ee[k]));
          float wg = hi ? ef.y : ef.x;
          float2 r01 = __half22float2(i2h((int)rr[k].x));
          float2 r23 = __half22float2(i2h((int)rr[k].y));
          se += wg;
          acc.x = fmaf(wg, r01.x, acc.x);
          acc.y = fmaf(wg, r01.y, acc.y);
          acc.z = fmaf(wg, r23.x, acc.z);
          acc.w = fmaf(wg, r23.y, acc.w);
        }
      }
      for (; j < cnt; ++j) {
        int s0 = __shfl(sl, j, 32), e0 = __shfl(epk, j, 32);
        float2 ef = __half22float2(i2h(e0));
        float wg = hi ? ef.y : ef.x;
        uint2 rv = *(const uint2*)&h1h[(size_t)s0 * 64 + q * 2];
        float2 r01 = __half22float2(i2h((int)rv.x));
        float2 r23 = __half22float2(i2h((int)rv.y));
        se += wg;
        acc.x = fmaf(wg, r01.x, acc.x);
        acc.y = fmaf(wg, r01.y, acc.y);
        acc.z = fmaf(wg, r23.x, acc.z);
        acc.w = fmaf(wg, r23.y, acc.w);
      }
    }
    if (act) {
      float inv = 1.f / se;
      float4 o;
      o.x = fmaf(acc.x, inv, bias.x);
      o.y = fmaf(acc.y, inv, bias.y);
      o.z = fmaf(acc.z, inv, bias.z);
      o.w = fmaf(acc.w, inv, bias.w);
      unsigned p01 = (unsigned)h2i(__floats2half2_rn(o.x, o.y));
      unsigned p23 = (unsigned)h2i(__floats2half2_rn(o.z, o.w));
      *(uint2*)&v1h[(size_t)n * 64 + q * 2] = make_uint2(p01, p23);
      bns.x += o.x; bns.y += o.y; bns.z += o.z; bns.w += o.w;
      bnq.x += o.x * o.x; bnq.y += o.y * o.y; bnq.z += o.z * o.z; bnq.w += o.w * o.w;
    }
  }
  __shared__ float4 reds[4][64], redq[4][64];
  reds[w][lane] = bns; redq[w][lane] = bnq;
  __syncthreads();
  if (t < 128) {
    int qq = t >> 2, ii = t & 3;
    float s = 0.f, sq = 0.f;
#pragma unroll
    for (int w2 = 0; w2 < 4; ++w2) {
      s  += (&reds[w2][qq].x)[ii] + (&reds[w2][qq + 32].x)[ii];
      sq += (&redq[w2][qq].x)[ii] + (&redq[w2][qq + 32].x)[ii];
    }
    atomicAdd(&stats[t], s);
    atomicAdd(&stats[128 + t], sq);
  }
}

// ====== GEMM2: h2 = relu(bn(v1h)) @ W2 (N x 128 @ 128 x 64), padded Xl, BN in-block ======
__global__ __launch_bounds__(256) void k_gemm2(
    const unsigned* __restrict__ v1h, const float* __restrict__ W2,
    const float* __restrict__ stats, const float* __restrict__ g1, const float* __restrict__ be1,
    const float* __restrict__ att_s, const float* __restrict__ att_d,
    unsigned* __restrict__ h2h, float* __restrict__ a2s, float* __restrict__ a2d,
    int N, float rcpN)
{
  __shared__ float Wl[128][64];
  __shared__ float Xl[64][132];
  __shared__ float kc[128], sc[128];
  int t = threadIdx.x;
  if (t < 128) {
    float mu = stats[t] * rcpN;
    float var = stats[128 + t] * rcpN - mu * mu;
    float kk = g1[t] * rsqrtf(var + 1e-5f);
    kc[t] = kk; sc[t] = be1[t] - mu * kk;
  }
  const float4* W4 = (const float4*)W2;
  float4* Wl4 = (float4*)&Wl[0][0];
#pragma unroll
  for (int i = 0; i < 8; ++i) Wl4[t + i * 256] = W4[t + i * 256];
  __syncthreads();
  int row0 = blockIdx.x * 64;
#pragma unroll
  for (int i = 0; i < 8; ++i) {
    int id = t + i * 256;
    int r = id >> 5, c4 = id & 31;
    int gr = row0 + r;
    uint2 pv = (gr < N) ? *(const uint2*)&v1h[(size_t)gr * 64 + c4 * 2] : make_uint2(0, 0);
    float2 a01 = __half22float2(i2h((int)pv.x));
    float2 a23 = __half22float2(i2h((int)pv.y));
    int f0 = c4 * 4;
    float4 o;
    o.x = fmaxf(a01.x * kc[f0]     + sc[f0],     0.f);
    o.y = fmaxf(a01.y * kc[f0 + 1] + sc[f0 + 1], 0.f);
    o.z = fmaxf(a23.x * kc[f0 + 2] + sc[f0 + 2], 0.f);
    o.w = fmaxf(a23.y * kc[f0 + 3] + sc[f0 + 3], 0.f);
    *(float4*)&Xl[r][c4 * 4] = o;
  }
  __syncthreads();
  int cg = t & 15, rg = t >> 4;
  float acc[4][4] = {};
#pragma unroll 2
  for (int k = 0; k < 128; k += 4) {
    float4 xv[4];
#pragma unroll
    for (int rr = 0; rr < 4; ++rr) xv[rr] = *(const float4*)&Xl[rg * 4 + rr][k];
#pragma unroll
    for (int kk = 0; kk < 4; ++kk) {
      float4 wv = *(const float4*)&Wl[k + kk][cg * 4];
#pragma unroll
      for (int rr = 0; rr < 4; ++rr) {
        float xs = (&xv[rr].x)[kk];
        acc[rr][0] = fmaf(xs, wv.x, acc[rr][0]);
        acc[rr][1] = fmaf(xs, wv.y, acc[rr][1]);
        acc[rr][2] = fmaf(xs, wv.z, acc[rr][2]);
        acc[rr][3] = fmaf(xs, wv.w, acc[rr][3]);
      }
    }
  }
  int col = cg * 4;
  float4 asv = *(const float4*)&att_s[col];
  float4 adv = *(const float4*)&att_d[col];
#pragma unroll
  for (int rr = 0; rr < 4; ++rr) {
    int gr = row0 + rg * 4 + rr;
    float ps = acc[rr][0] * asv.x + acc[rr][1] * asv.y + acc[rr][2] * asv.z + acc[rr][3] * asv.w;
    float pd = acc[rr][0] * adv.x + acc[rr][1] * adv.y + acc[rr][2] * adv.z + acc[rr][3] * adv.w;
    ps += __shfl_xor(ps, 1); ps += __shfl_xor(ps, 2); ps += __shfl_xor(ps, 4); ps += __shfl_xor(ps, 8);
    pd += __shfl_xor(pd, 1); pd += __shfl_xor(pd, 2); pd += __shfl_xor(pd, 4); pd += __shfl_xor(pd, 8);
    if (gr < N) {
      unsigned p01 = (unsigned)h2i(__floats2half2_rn(acc[rr][0], acc[rr][1]));
      unsigned p23 = (unsigned)h2i(__floats2half2_rn(acc[rr][2], acc[rr][3]));
      *(uint2*)&h2h[(size_t)gr * 32 + cg * 2] = make_uint2(p01, p23);
      if ((t & 15) == 0) { a2s[gr] = ps; a2d[gr] = pd; }
    }
  }
}

// ====== Aggregate layer 2: TWO nodes per wave (32 lanes each, 2 feats/lane via uint),
//        16 rows in flight per half-wave ======
__global__ __launch_bounds__(256) void k_agg2(
    const int* __restrict__ rowptr, const int* __restrict__ colx,
    const unsigned* __restrict__ h2h, const float* __restrict__ a2s,
    const float* __restrict__ a2d, const float* __restrict__ b2,
    unsigned* __restrict__ v2h, float* __restrict__ stats, int N, int TW)
{
  int t = threadIdx.x;
  int w = t >> 6, lane = t & 63;
  int g = lane >> 5, q = lane & 31;
  float2 bias = *(const float2*)&b2[q * 2];
  float2 bns = {0,0}, bnq = {0,0};
  int W = blockIdx.x * 4 + w;
  int iters = (N + 2 * TW - 1) / (2 * TW);
  for (int it = 0; it < iters; ++it) {
    int n = (it * TW + W) * 2 + g;
    bool act = n < N;
    int start = 0, end = 0;
    float ad = 0.f;
    if (act) { start = rowptr[n]; end = rowptr[n + 1]; ad = a2d[n]; }
    float se = 0.f;
    float2 acc = {0,0};
    for (int base = start; base < end; base += 32) {
      int cnt = end - base; if (cnt > 32) cnt = 32;
      int sl = 0; float ev = 0.f;
      if (q < cnt) {
        sl = colx[base + q];
        float av = a2s[sl] + ad;
        av = (av > 0.f) ? av : LEAKY * av;
        ev = __expf(av);
      }
      int j = 0;
      int lim16 = cnt & ~15;
      for (; j < lim16; j += 16) {
        int ss[16]; float ee[16];
#pragma unroll
        for (int k = 0; k < 16; ++k) { ss[k] = __shfl(sl, j + k, 32); ee[k] = __shfl(ev, j + k, 32); }
        unsigned rr[16];
#pragma unroll
        for (int k = 0; k < 16; ++k) rr[k] = h2h[(size_t)ss[k] * 32 + q];
#pragma unroll
        for (int k = 0; k < 16; ++k) {
          float2 rf = __half22float2(i2h((int)rr[k]));
          se += ee[k];
          acc.x = fmaf(ee[k], rf.x, acc.x);
          acc.y = fmaf(ee[k], rf.y, acc.y);
        }
      }
      int lim8 = cnt & ~7;
      for (; j < lim8; j += 8) {
        int ss[8]; float ee[8];
#pragma unroll
        for (int k = 0; k < 8; ++k) { ss[k] = __shfl(sl, j + k, 32); ee[k] = __shfl(ev, j + k, 32); }
        unsigned rr[8];
#pragma unroll
        for (int k = 0; k < 8; ++k) rr[k] = h2h[(size_t)ss[k] * 32 + q];
#pragma unroll
        for (int k = 0; k < 8; ++k) {
          float2 rf = __half22float2(i2h((int)rr[k]));
          se += ee[k];
          acc.x = fmaf(ee[k], rf.x, acc.x);
          acc.y = fmaf(ee[k], rf.y, acc.y);
        }
      }
      for (; j < cnt; ++j) {
        int s0 = __shfl(sl, j, 32);
        float e0 = __shfl(ev, j, 32);
        float2 rf = __half22float2(i2h((int)h2h[(size_t)s0 * 32 + q]));
        se += e0;
        acc.x = fmaf(e0, rf.x, acc.x);
        acc.y = fmaf(e0, rf.y, acc.y);
      }
    }
    if (act) {
      float inv = 1.f / se;
      float2 o;
      o.x = fmaf(acc.x, inv, bias.x);
      o.y = fmaf(acc.y, inv, bias.y);
      v2h[(size_t)n * 32 + q] = (unsigned)h2i(__floats2half2_rn(o.x, o.y));
      bns.x += o.x; bns.y += o.y;
      bnq.x += o.x * o.x; bnq.y += o.y * o.y;
    }
  }
  __shared__ float2 reds[4][64], redq[4][64];
  reds[w][lane] = bns; redq[w][lane] = bnq;
  __syncthreads();
  if (t < 64) {
    int qq = t >> 1, ii = t & 1;
    float s = 0.f, sq = 0.f;
#pragma unroll
    for (int w2 = 0; w2 < 4; ++w2) {
      s  += (&reds[w2][qq].x)[ii] + (&reds[w2][qq + 32].x)[ii];
      sq += (&redq[w2][qq].x)[ii] + (&redq[w2][qq + 32].x)[ii];
    }
    atomicAdd(&stats[t], s);
    atomicAdd(&stats[64 + t], sq);
  }
}

// ================= Final: out = relu(bn(v2h)) @ linW + linb, BN inline =================
__global__ __launch_bounds__(256) void k_out(
    const __half* __restrict__ v2h, const float* __restrict__ stats,
    const float* __restrict__ g2, const float* __restrict__ be2,
    const float* __restrict__ linW, const float* __restrict__ linb,
    float* __restrict__ out, int N, float rcpN)
{
  int lane = threadIdx.x & 63;
  int n = blockIdx.x * 4 + (threadIdx.x >> 6);
  if (n >= N) return;
  float mu = stats[lane] * rcpN;
  float var = stats[64 + lane] * rcpN - mu * mu;
  float kk = g2[lane] * rsqrtf(var + 1e-5f);
  float sh = be2[lane] - mu * kk;
  float v = __half2float(v2h[(size_t)n * 64 + lane]);
  float hn = fmaxf(v * kk + sh, 0.f);
  float p = hn * linW[lane];
#pragma unroll
  for (int off = 32; off; off >>= 1) p += __shfl_xor(p, off);
  if (lane == 0) out[n] = p + linb[0];
}

extern "C" void kernel_launch(void* const* d_in, const int* in_sizes, int n_in,
                              void* d_out, int out_size, void* d_ws, size_t ws_size,
                              hipStream_t stream)
{
  const float* x    = (const float*)d_in[0];
  const int*   ei   = (const int*)d_in[1];
  const float* W1   = (const float*)d_in[2];
  const float* as1  = (const float*)d_in[3];
  const float* ad1  = (const float*)d_in[4];
  const float* b1   = (const float*)d_in[5];
  const float* g1   = (const float*)d_in[6];
  const float* be1  = (const float*)d_in[7];
  const float* W2   = (const float*)d_in[8];
  const float* as2  = (const float*)d_in[9];
  const float* ad2  = (const float*)d_in[10];
  const float* b2   = (const float*)d_in[11];
  const float* g2   = (const float*)d_in[12];
  const float* be2  = (const float*)d_in[13];
  const float* linW = (const float*)d_in[14];
  const float* linb = (const float*)d_in[15];
  float* out = (float*)d_out;

  int N = in_sizes[0] / 128;
  int E = in_sizes[1] / 2;
  int Etot = E + N;
  float rcpN = 1.f / (float)N;

  float* ws = (float*)d_ws;
  size_t o = 0;
  float* H1HF = ws + o; o += (size_t)N * 64;   // h1 fp16 (N x 128 halves); later h2h (N x 64 halves)
  float* V1HF = ws + o; o += (size_t)N * 64;   // v1 fp16; later v2h
  float* A1S  = ws + o; o += (size_t)N * 2;
  float* A1D  = ws + o; o += (size_t)N * 2;
  float* A2S  = ws + o; o += N;
  float* A2D  = ws + o; o += N;
  float* ST1  = ws + o; o += 256;              // zero-region start
  float* ST2  = ws + o; o += 128;              // zero-region end (384 floats)
  int* ROWPTR = (int*)(ws + o); o += (size_t)N + 1;
  int* COL    = (int*)(ws + o); o += (size_t)Etot;
  int* DEG    = (int*)(ws + o); o += N;
  int* PART   = (int*)(ws + o); o += 64;
  unsigned* H1H = (unsigned*)H1HF;
  unsigned* H2H = (unsigned*)H1HF;
  unsigned* V1H = (unsigned*)V1HF;
  unsigned* V2H = (unsigned*)V1HF;

  hipMemsetAsync(ST1, 0, 384 * 4, stream);
  hipMemsetAsync(DEG, 0, (size_t)N * 4, stream);

  int ebk = (Etot + 255) / 256;
  int nb = (N + 1024) / 1024;
  int gb = (N + 63) / 64;
  const int AB = 2048;                         // 8192 waves
  const int TW = AB * 4;

  k_hist<<<ebk, 256, 0, stream>>>(ei, DEG, E, Etot);
  k_scan_blk<<<nb, 256, 0, stream>>>(DEG, ROWPTR, PART, N);
  k_add_off<<<nb, 256, 0, stream>>>(ROWPTR, PART, DEG, N, nb);
  k_scatter<<<ebk, 256, 0, stream>>>(ei, DEG, COL, E, Etot);

  k_gemm1<<<gb, 256, 0, stream>>>(x, W1, as1, ad1, H1H, A1S, A1D, N);
  k_agg1<<<AB, 256, 0, stream>>>(ROWPTR, COL, H1H, A1S, A1D, b1, V1H, ST1, N, TW);
  k_gemm2<<<gb, 256, 0, stream>>>(V1H, W2, ST1, g1, be1, as2, ad2, H2H, A2S, A2D, N, rcpN);
  k_agg2<<<AB, 256, 0, stream>>>(ROWPTR, COL, H2H, A2S, A2D, b2, V2H, ST2, N, TW);
  k_out<<<(N + 3) / 4, 256, 0, stream>>>((const __half*)V2H, ST2, g2, be2, linW, linb, out, N, rcpN);
}